// Round 1
// baseline (150.536 us; speedup 1.0000x reference)
//
#include <hip/hip_runtime.h>
#include <math.h>

#define HW 384
#define PLANE (HW*HW)   // 147456

// ---- workspace layout (float-index offsets) ----
#define WT1_OFF   0                         // 7200 floats: [c*25+tap][32 o]
#define SC1_OFF   7296                      // 32
#define SH1_OFF   7328                      // 32
#define WT2_OFF   7360                      // 6400: [ci*25+tap][8 o]
#define SC2_OFF   13760                     // 8
#define SH2_OFF   13768                     // 8
#define W3_OFF    13776                     // 200: [ci*25+tap]
#define SC3_OFF   13976                     // 1
#define SH3_OFF   13977                     // 1
#define FWT_OFF   13984                     // 5488: [(dz*7+dy)*7+dx][c*4+o]  (16B aligned)
#define H1_OFF    32768                     // 32*PLANE
#define H2_OFF    (32768 + 32*PLANE)        // 8*PLANE
#define DEPTH_OFF (32768 + 40*PLANE)        // PLANE int32

// ---------------- prep: fold BN, transpose weights ----------------
__global__ void prep_kernel(
    const float* __restrict__ c1w, const float* __restrict__ c1b,
    const float* __restrict__ g1, const float* __restrict__ b1,
    const float* __restrict__ m1, const float* __restrict__ v1,
    const float* __restrict__ c2w, const float* __restrict__ c2b,
    const float* __restrict__ g2, const float* __restrict__ b2,
    const float* __restrict__ m2, const float* __restrict__ v2,
    const float* __restrict__ c3w, const float* __restrict__ c3b,
    const float* __restrict__ g3, const float* __restrict__ b3,
    const float* __restrict__ m3, const float* __restrict__ v3,
    const float* __restrict__ fw, float* __restrict__ W)
{
    int tid = threadIdx.x;
    // conv1 weights: OIHW (32,9,5,5) -> [ct][o]
    for (int i = tid; i < 7200; i += 256) {
        int o = i & 31, ct = i >> 5;
        W[WT1_OFF + i] = c1w[o * 225 + ct];
    }
    if (tid < 32) {
        float sc = g1[tid] / sqrtf(v1[tid] + 1e-5f);
        W[SC1_OFF + tid] = sc;
        W[SH1_OFF + tid] = (c1b[tid] - m1[tid]) * sc + b1[tid];
    }
    // conv2 weights: (8,32,5,5) -> [ct][o]
    for (int i = tid; i < 6400; i += 256) {
        int o = i & 7, ct = i >> 3;
        W[WT2_OFF + i] = c2w[o * 800 + ct];
    }
    if (tid < 8) {
        float sc = g2[tid] / sqrtf(v2[tid] + 1e-5f);
        W[SC2_OFF + tid] = sc;
        W[SH2_OFF + tid] = (c2b[tid] - m2[tid]) * sc + b2[tid];
    }
    // conv3 weights (1,8,5,5) already [ct]
    if (tid < 200) W[W3_OFF + tid] = c3w[tid];
    if (tid == 0) {
        float sc = g3[0] / sqrtf(v3[0] + 1e-5f);
        W[SC3_OFF] = sc;
        W[SH3_OFF] = (c3b[0] - m3[0]) * sc + b3[0];
    }
    // f_w: OIDHW (4,4,7,7,7) -> [s=(dz*7+dy)*7+dx][c*4+o]
    for (int i = tid; i < 5488; i += 256) {
        int s = i >> 4, r = i & 15, c = r >> 2, o = r & 3;
        W[FWT_OFF + i] = fw[o * 1372 + c * 343 + s];
    }
}

// ---------------- conv1: 9 -> 32, 5x5, BN+ReLU ----------------
__global__ __launch_bounds__(256) void conv1_kernel(
    const float* __restrict__ light, const float* __restrict__ albedo,
    const float* __restrict__ normals, const float* __restrict__ W,
    float* __restrict__ h1)
{
    __shared__ float tile[9][12][36];
    int tid = threadIdx.x;
    int tx = tid & 31, ty = tid >> 5;
    int bx = blockIdx.x % 12, by = blockIdx.x / 12;
    int x0 = bx * 32 - 2, y0 = by * 8 - 2;

    for (int p = tid; p < 432; p += 256) {
        int py = p / 36, px = p % 36;
        int gy = y0 + py, gx = x0 + px;
        bool ok = ((unsigned)gy < (unsigned)HW) && ((unsigned)gx < (unsigned)HW);
        int gofs = ok ? (gy * HW + gx) : 0;
#pragma unroll
        for (int c = 0; c < 3; ++c) {
            float a = light[c * PLANE + gofs];
            float b = albedo[c * PLANE + gofs];
            float n = normals[c * PLANE + gofs];
            tile[c][py][px]     = ok ? a : 0.f;
            tile[c + 3][py][px] = ok ? b : 0.f;
            tile[c + 6][py][px] = ok ? n : 0.f;
        }
    }
    __syncthreads();

    float acc[32];
#pragma unroll
    for (int o = 0; o < 32; ++o) acc[o] = 0.f;

    const float4* w4 = (const float4*)(W + WT1_OFF);
#pragma unroll 1
    for (int c = 0; c < 9; ++c) {
#pragma unroll 1
        for (int ky = 0; ky < 5; ++ky) {
#pragma unroll
            for (int kx = 0; kx < 5; ++kx) {
                float v = tile[c][ty + ky][tx + kx];
                int tap = (c * 5 + ky) * 5 + kx;
                const float4* wp = w4 + tap * 8;
#pragma unroll
                for (int o4 = 0; o4 < 8; ++o4) {
                    float4 wv = wp[o4];
                    acc[o4 * 4 + 0] = fmaf(v, wv.x, acc[o4 * 4 + 0]);
                    acc[o4 * 4 + 1] = fmaf(v, wv.y, acc[o4 * 4 + 1]);
                    acc[o4 * 4 + 2] = fmaf(v, wv.z, acc[o4 * 4 + 2]);
                    acc[o4 * 4 + 3] = fmaf(v, wv.w, acc[o4 * 4 + 3]);
                }
            }
        }
    }

    int gy = by * 8 + ty, gx = bx * 32 + tx;
    int pix = gy * HW + gx;
#pragma unroll
    for (int o = 0; o < 32; ++o) {
        float r = fmaf(acc[o], W[SC1_OFF + o], W[SH1_OFF + o]);
        h1[o * PLANE + pix] = fmaxf(r, 0.f);
    }
}

// ---------------- conv2: 32 -> 8, 5x5, BN+ReLU ----------------
__global__ __launch_bounds__(256) void conv2_kernel(
    const float* __restrict__ h1, const float* __restrict__ W,
    float* __restrict__ h2)
{
    __shared__ float tile[32][12][36];
    int tid = threadIdx.x;
    int tx = tid & 31, ty = tid >> 5;
    int bx = blockIdx.x % 12, by = blockIdx.x / 12;
    int x0 = bx * 32 - 2, y0 = by * 8 - 2;

    for (int p = tid; p < 432; p += 256) {
        int py = p / 36, px = p % 36;
        int gy = y0 + py, gx = x0 + px;
        bool ok = ((unsigned)gy < (unsigned)HW) && ((unsigned)gx < (unsigned)HW);
        int gofs = ok ? (gy * HW + gx) : 0;
#pragma unroll
        for (int c = 0; c < 32; ++c) {
            float v = h1[c * PLANE + gofs];
            tile[c][py][px] = ok ? v : 0.f;
        }
    }
    __syncthreads();

    float acc[8];
#pragma unroll
    for (int o = 0; o < 8; ++o) acc[o] = 0.f;

    const float4* w4 = (const float4*)(W + WT2_OFF);
#pragma unroll 1
    for (int c = 0; c < 32; ++c) {
#pragma unroll
        for (int ky = 0; ky < 5; ++ky) {
#pragma unroll
            for (int kx = 0; kx < 5; ++kx) {
                float v = tile[c][ty + ky][tx + kx];
                int tap = (c * 5 + ky) * 5 + kx;
                float4 w0 = w4[tap * 2 + 0];
                float4 w1 = w4[tap * 2 + 1];
                acc[0] = fmaf(v, w0.x, acc[0]);
                acc[1] = fmaf(v, w0.y, acc[1]);
                acc[2] = fmaf(v, w0.z, acc[2]);
                acc[3] = fmaf(v, w0.w, acc[3]);
                acc[4] = fmaf(v, w1.x, acc[4]);
                acc[5] = fmaf(v, w1.y, acc[5]);
                acc[6] = fmaf(v, w1.z, acc[6]);
                acc[7] = fmaf(v, w1.w, acc[7]);
            }
        }
    }

    int gy = by * 8 + ty, gx = bx * 32 + tx;
    int pix = gy * HW + gx;
#pragma unroll
    for (int o = 0; o < 8; ++o) {
        float r = fmaf(acc[o], W[SC2_OFF + o], W[SH2_OFF + o]);
        h2[o * PLANE + pix] = fmaxf(r, 0.f);
    }
}

// ---------------- conv3: 8 -> 1, 5x5, BN + sigmoid + floor -> depth ----------------
__global__ __launch_bounds__(256) void conv3_kernel(
    const float* __restrict__ h2, const float* __restrict__ W,
    int* __restrict__ depth)
{
    __shared__ float tile[8][12][36];
    int tid = threadIdx.x;
    int tx = tid & 31, ty = tid >> 5;
    int bx = blockIdx.x % 12, by = blockIdx.x / 12;
    int x0 = bx * 32 - 2, y0 = by * 8 - 2;

    for (int p = tid; p < 432; p += 256) {
        int py = p / 36, px = p % 36;
        int gy = y0 + py, gx = x0 + px;
        bool ok = ((unsigned)gy < (unsigned)HW) && ((unsigned)gx < (unsigned)HW);
        int gofs = ok ? (gy * HW + gx) : 0;
#pragma unroll
        for (int c = 0; c < 8; ++c) {
            float v = h2[c * PLANE + gofs];
            tile[c][py][px] = ok ? v : 0.f;
        }
    }
    __syncthreads();

    float a = 0.f;
#pragma unroll 1
    for (int c = 0; c < 8; ++c) {
#pragma unroll
        for (int ky = 0; ky < 5; ++ky) {
#pragma unroll
            for (int kx = 0; kx < 5; ++kx) {
                a = fmaf(tile[c][ty + ky][tx + kx], W[W3_OFF + (c * 5 + ky) * 5 + kx], a);
            }
        }
    }
    float y = fmaf(a, W[SC3_OFF], W[SH3_OFF]);
    float s = 1.f / (1.f + expf(-y));
    int d = (int)floorf(s * (16.f - 1e-5f));

    int gy = by * 8 + ty, gx = bx * 32 + tx;
    depth[gy * HW + gx] = d;
}

// ---------------- final: sparse 3d conv gather + divide + albedo ----------------
__global__ __launch_bounds__(256) void final_kernel(
    const float* __restrict__ light, const float* __restrict__ albedo,
    const float* __restrict__ W, const float* __restrict__ fb,
    float* __restrict__ out)
{
    __shared__ float fw[5488];
    __shared__ float ltile[3][14][38];
    __shared__ int   dtile[14][38];

    int tid = threadIdx.x;
    int tx = tid & 31, ty = tid >> 5;
    int bx = blockIdx.x % 12, by = blockIdx.x / 12;
    int x0 = bx * 32 - 3, y0 = by * 8 - 3;

    for (int i = tid; i < 5488; i += 256) fw[i] = W[FWT_OFF + i];

    const int* dmap = ((const int*)W) + DEPTH_OFF;
    for (int p = tid; p < 14 * 38; p += 256) {
        int py = p / 38, px = p % 38;
        int gy = y0 + py, gx = x0 + px;
        bool ok = ((unsigned)gy < (unsigned)HW) && ((unsigned)gx < (unsigned)HW);
        int gofs = ok ? (gy * HW + gx) : 0;
        int dv = dmap[gofs];
        dtile[py][px] = ok ? dv : -1000;
#pragma unroll
        for (int c = 0; c < 3; ++c) {
            float lv = light[c * PLANE + gofs];
            ltile[c][py][px] = ok ? lv : 0.f;
        }
    }
    __syncthreads();

    int d0 = dtile[ty + 3][tx + 3];
    float a0 = fb[0], a1 = fb[1], a2 = fb[2], a3 = fb[3];
    const float4* fw4 = (const float4*)fw;

#pragma unroll 1
    for (int dy = 0; dy < 7; ++dy) {
#pragma unroll
        for (int dx = 0; dx < 7; ++dx) {
            int dd = dtile[ty + dy][tx + dx];
            int dz = dd - d0 + 3;
            if ((unsigned)dz < 7u) {
                int s = (dz * 7 + dy) * 7 + dx;
                float4 w0 = fw4[s * 4 + 0];
                float4 w1 = fw4[s * 4 + 1];
                float4 w2 = fw4[s * 4 + 2];
                float4 w3 = fw4[s * 4 + 3];
                float l0 = ltile[0][ty + dy][tx + dx];
                float l1 = ltile[1][ty + dy][tx + dx];
                float l2 = ltile[2][ty + dy][tx + dx];
                a0 += l0 * w0.x + l1 * w1.x + l2 * w2.x + w3.x;
                a1 += l0 * w0.y + l1 * w1.y + l2 * w2.y + w3.y;
                a2 += l0 * w0.z + l1 * w1.z + l2 * w2.z + w3.z;
                a3 += l0 * w0.w + l1 * w1.w + l2 * w2.w + w3.w;
            }
        }
    }

    int gy = by * 8 + ty, gx = bx * 32 + tx;
    int pix = gy * HW + gx;
    out[0 * PLANE + pix] = a0 / a3 * albedo[0 * PLANE + pix];
    out[1 * PLANE + pix] = a1 / a3 * albedo[1 * PLANE + pix];
    out[2 * PLANE + pix] = a2 / a3 * albedo[2 * PLANE + pix];
}

extern "C" void kernel_launch(void* const* d_in, const int* in_sizes, int n_in,
                              void* d_out, int out_size, void* d_ws, size_t ws_size,
                              hipStream_t stream) {
    const float* light     = (const float*)d_in[0];
    const float* albedo    = (const float*)d_in[1];
    const float* normals   = (const float*)d_in[2];
    // d_in[3] positions: unused by the reference
    const float* c1_w = (const float*)d_in[4];
    const float* c1_b = (const float*)d_in[5];
    const float* bn1_g = (const float*)d_in[6];
    const float* bn1_b = (const float*)d_in[7];
    const float* bn1_m = (const float*)d_in[8];
    const float* bn1_v = (const float*)d_in[9];
    const float* c2_w = (const float*)d_in[10];
    const float* c2_b = (const float*)d_in[11];
    const float* bn2_g = (const float*)d_in[12];
    const float* bn2_b = (const float*)d_in[13];
    const float* bn2_m = (const float*)d_in[14];
    const float* bn2_v = (const float*)d_in[15];
    const float* c3_w = (const float*)d_in[16];
    const float* c3_b = (const float*)d_in[17];
    const float* bn3_g = (const float*)d_in[18];
    const float* bn3_b = (const float*)d_in[19];
    const float* bn3_m = (const float*)d_in[20];
    const float* bn3_v = (const float*)d_in[21];
    const float* f_w = (const float*)d_in[22];
    const float* f_b = (const float*)d_in[23];

    float* W = (float*)d_ws;
    float* h1 = W + H1_OFF;
    float* h2 = W + H2_OFF;
    int* depth = ((int*)d_ws) + DEPTH_OFF;
    float* out = (float*)d_out;

    hipLaunchKernelGGL(prep_kernel, dim3(1), dim3(256), 0, stream,
                       c1_w, c1_b, bn1_g, bn1_b, bn1_m, bn1_v,
                       c2_w, c2_b, bn2_g, bn2_b, bn2_m, bn2_v,
                       c3_w, c3_b, bn3_g, bn3_b, bn3_m, bn3_v,
                       f_w, W);
    hipLaunchKernelGGL(conv1_kernel, dim3(576), dim3(256), 0, stream,
                       light, albedo, normals, W, h1);
    hipLaunchKernelGGL(conv2_kernel, dim3(576), dim3(256), 0, stream,
                       h1, W, h2);
    hipLaunchKernelGGL(conv3_kernel, dim3(576), dim3(256), 0, stream,
                       h2, W, depth);
    hipLaunchKernelGGL(final_kernel, dim3(576), dim3(256), 0, stream,
                       light, albedo, W, f_b, out);
}

// Round 2
// 123.063 us; speedup vs baseline: 1.2232x; 1.2232x over previous
//
#include <hip/hip_runtime.h>
#include <math.h>

#define HW 384
#define PLANE (HW*HW)   // 147456

// ---- workspace layout (float-index offsets) ----
#define WT1_OFF   0                         // 7200 floats: [c*25+tap][32 o]
#define SC1_OFF   7296                      // 32
#define SH1_OFF   7328                      // 32
#define WT2_OFF   7360                      // 6400: [ci*25+tap][8 o]
#define SC2_OFF   13760                     // 8
#define SH2_OFF   13768                     // 8
#define W3_OFF    13776                     // 200: [ci*25+tap]
#define SC3_OFF   13976                     // 1
#define SH3_OFF   13977                     // 1
#define FWT_OFF   13984                     // 5488: [(dz*7+dy)*7+dx][c*4+o]  (16B aligned)
#define H1_OFF    32768                     // 32*PLANE
#define H2_OFF    (32768 + 32*PLANE)        // 8*PLANE
#define DEPTH_OFF (32768 + 40*PLANE)        // PLANE int32

// ---------------- prep: fold BN, transpose weights (multi-block) ----------------
__global__ void prep_kernel(
    const float* __restrict__ c1w, const float* __restrict__ c1b,
    const float* __restrict__ g1, const float* __restrict__ b1,
    const float* __restrict__ m1, const float* __restrict__ v1,
    const float* __restrict__ c2w, const float* __restrict__ c2b,
    const float* __restrict__ g2, const float* __restrict__ b2,
    const float* __restrict__ m2, const float* __restrict__ v2,
    const float* __restrict__ c3w, const float* __restrict__ c3b,
    const float* __restrict__ g3, const float* __restrict__ b3,
    const float* __restrict__ m3, const float* __restrict__ v3,
    const float* __restrict__ fw, float* __restrict__ W)
{
    int gid = blockIdx.x * 256 + threadIdx.x;
    int gstr = gridDim.x * 256;
    // conv1 weights: OIHW (32,9,5,5) -> [ct][o]
    for (int i = gid; i < 7200; i += gstr) {
        int o = i & 31, ct = i >> 5;
        W[WT1_OFF + i] = c1w[o * 225 + ct];
    }
    // conv2 weights: (8,32,5,5) -> [ct][o]
    for (int i = gid; i < 6400; i += gstr) {
        int o = i & 7, ct = i >> 3;
        W[WT2_OFF + i] = c2w[o * 800 + ct];
    }
    // f_w: OIDHW (4,4,7,7,7) -> [s=(dz*7+dy)*7+dx][c*4+o]
    for (int i = gid; i < 5488; i += gstr) {
        int s = i >> 4, r = i & 15, c = r >> 2, o = r & 3;
        W[FWT_OFF + i] = fw[o * 1372 + c * 343 + s];
    }
    if (blockIdx.x == 0) {
        int tid = threadIdx.x;
        if (tid < 32) {
            float sc = g1[tid] / sqrtf(v1[tid] + 1e-5f);
            W[SC1_OFF + tid] = sc;
            W[SH1_OFF + tid] = (c1b[tid] - m1[tid]) * sc + b1[tid];
        }
        if (tid < 8) {
            float sc = g2[tid] / sqrtf(v2[tid] + 1e-5f);
            W[SC2_OFF + tid] = sc;
            W[SH2_OFF + tid] = (c2b[tid] - m2[tid]) * sc + b2[tid];
        }
        if (tid < 200) W[W3_OFF + tid] = c3w[tid];
        if (tid == 0) {
            float sc = g3[0] / sqrtf(v3[0] + 1e-5f);
            W[SC3_OFF] = sc;
            W[SH3_OFF] = (c3b[0] - m3[0]) * sc + b3[0];
        }
    }
}

// ---------------- conv1: 9 -> 32, 5x5, BN+ReLU ----------------
__global__ __launch_bounds__(256) void conv1_kernel(
    const float* __restrict__ light, const float* __restrict__ albedo,
    const float* __restrict__ normals, const float* __restrict__ W,
    float* __restrict__ h1)
{
    __shared__ float tile[9][12][36];
    int tid = threadIdx.x;
    int tx = tid & 31, ty = tid >> 5;
    int bx = blockIdx.x % 12, by = blockIdx.x / 12;
    int x0 = bx * 32 - 2, y0 = by * 8 - 2;

    for (int p = tid; p < 432; p += 256) {
        int py = p / 36, px = p % 36;
        int gy = y0 + py, gx = x0 + px;
        bool ok = ((unsigned)gy < (unsigned)HW) && ((unsigned)gx < (unsigned)HW);
        int gofs = ok ? (gy * HW + gx) : 0;
#pragma unroll
        for (int c = 0; c < 3; ++c) {
            float a = light[c * PLANE + gofs];
            float b = albedo[c * PLANE + gofs];
            float n = normals[c * PLANE + gofs];
            tile[c][py][px]     = ok ? a : 0.f;
            tile[c + 3][py][px] = ok ? b : 0.f;
            tile[c + 6][py][px] = ok ? n : 0.f;
        }
    }
    __syncthreads();

    float acc[32];
#pragma unroll
    for (int o = 0; o < 32; ++o) acc[o] = 0.f;

    const float4* w4 = (const float4*)(W + WT1_OFF);
#pragma unroll 1
    for (int c = 0; c < 9; ++c) {
#pragma unroll 1
        for (int ky = 0; ky < 5; ++ky) {
#pragma unroll
            for (int kx = 0; kx < 5; ++kx) {
                float v = tile[c][ty + ky][tx + kx];
                int tap = (c * 5 + ky) * 5 + kx;
                const float4* wp = w4 + tap * 8;
#pragma unroll
                for (int o4 = 0; o4 < 8; ++o4) {
                    float4 wv = wp[o4];
                    acc[o4 * 4 + 0] = fmaf(v, wv.x, acc[o4 * 4 + 0]);
                    acc[o4 * 4 + 1] = fmaf(v, wv.y, acc[o4 * 4 + 1]);
                    acc[o4 * 4 + 2] = fmaf(v, wv.z, acc[o4 * 4 + 2]);
                    acc[o4 * 4 + 3] = fmaf(v, wv.w, acc[o4 * 4 + 3]);
                }
            }
        }
    }

    int gy = by * 8 + ty, gx = bx * 32 + tx;
    int pix = gy * HW + gx;
#pragma unroll
    for (int o = 0; o < 32; ++o) {
        float r = fmaf(acc[o], W[SC1_OFF + o], W[SH1_OFF + o]);
        h1[o * PLANE + pix] = fmaxf(r, 0.f);
    }
}

// ---------------- conv2: 32 -> 8, 5x5, BN+ReLU (chunked, double-buffered) ----------------
__global__ __launch_bounds__(256, 5) void conv2_kernel(
    const float* __restrict__ h1, const float* __restrict__ W,
    float* __restrict__ h2)
{
    __shared__ float tile[2][8][12][36];   // 2 x 13824 B
    int tid = threadIdx.x;
    int tx = tid & 31, ty = tid >> 5;
    int bx = blockIdx.x % 12, by = blockIdx.x / 12;
    int x0 = bx * 32 - 2, y0 = by * 8 - 2;

    int p0 = tid;
    int py0 = p0 / 36, px0 = p0 % 36;
    int gy0 = y0 + py0, gx0 = x0 + px0;
    bool ok0 = ((unsigned)gy0 < (unsigned)HW) && ((unsigned)gx0 < (unsigned)HW);
    int gofs0 = ok0 ? (gy0 * HW + gx0) : 0;

    int p1 = tid + 256;
    bool has1 = (p1 < 432);
    int py1 = p1 / 36, px1 = p1 % 36;
    int gy1 = y0 + py1, gx1 = x0 + px1;
    bool ok1 = has1 && ((unsigned)gy1 < (unsigned)HW) && ((unsigned)gx1 < (unsigned)HW);
    int gofs1 = ok1 ? (gy1 * HW + gx1) : 0;

    float acc[8];
#pragma unroll
    for (int o = 0; o < 8; ++o) acc[o] = 0.f;

    // stage chunk 0 into buffer 0
    {
        float* dst = &tile[0][0][0][0];
#pragma unroll
        for (int c = 0; c < 8; ++c) {
            float v = h1[c * PLANE + gofs0];
            dst[c * 432 + p0] = ok0 ? v : 0.f;
        }
        if (has1) {
#pragma unroll
            for (int c = 0; c < 8; ++c) {
                float v = h1[c * PLANE + gofs1];
                dst[c * 432 + p1] = ok1 ? v : 0.f;
            }
        }
    }
    __syncthreads();

#pragma unroll 1
    for (int k = 0; k < 4; ++k) {
        // stage chunk k+1 into the other buffer (issued before compute so
        // the global-load latency hides under this chunk's FMAs)
        if (k < 3) {
            const float* src = h1 + (k + 1) * 8 * PLANE;
            float* dst = &tile[(k + 1) & 1][0][0][0];
#pragma unroll
            for (int c = 0; c < 8; ++c) {
                float v = src[c * PLANE + gofs0];
                dst[c * 432 + p0] = ok0 ? v : 0.f;
            }
            if (has1) {
#pragma unroll
                for (int c = 0; c < 8; ++c) {
                    float v = src[c * PLANE + gofs1];
                    dst[c * 432 + p1] = ok1 ? v : 0.f;
                }
            }
        }

        const float* buf = &tile[k & 1][0][0][0];
        const float4* w4 = (const float4*)(W + WT2_OFF) + k * 8 * 25 * 2;
#pragma unroll 1
        for (int c = 0; c < 8; ++c) {
            const float* bc = buf + c * 432;
#pragma unroll
            for (int ky = 0; ky < 5; ++ky) {
#pragma unroll
                for (int kx = 0; kx < 5; ++kx) {
                    float v = bc[(ty + ky) * 36 + (tx + kx)];
                    int tap = c * 25 + ky * 5 + kx;
                    float4 w0 = w4[tap * 2 + 0];
                    float4 w1 = w4[tap * 2 + 1];
                    acc[0] = fmaf(v, w0.x, acc[0]);
                    acc[1] = fmaf(v, w0.y, acc[1]);
                    acc[2] = fmaf(v, w0.z, acc[2]);
                    acc[3] = fmaf(v, w0.w, acc[3]);
                    acc[4] = fmaf(v, w1.x, acc[4]);
                    acc[5] = fmaf(v, w1.y, acc[5]);
                    acc[6] = fmaf(v, w1.z, acc[6]);
                    acc[7] = fmaf(v, w1.w, acc[7]);
                }
            }
        }
        __syncthreads();
    }

    int gy = by * 8 + ty, gx = bx * 32 + tx;
    int pix = gy * HW + gx;
#pragma unroll
    for (int o = 0; o < 8; ++o) {
        float r = fmaf(acc[o], W[SC2_OFF + o], W[SH2_OFF + o]);
        h2[o * PLANE + pix] = fmaxf(r, 0.f);
    }
}

// ---------------- conv3: 8 -> 1, 5x5, BN + sigmoid + floor -> depth ----------------
__global__ __launch_bounds__(256) void conv3_kernel(
    const float* __restrict__ h2, const float* __restrict__ W,
    int* __restrict__ depth)
{
    __shared__ float tile[8][12][36];
    int tid = threadIdx.x;
    int tx = tid & 31, ty = tid >> 5;
    int bx = blockIdx.x % 12, by = blockIdx.x / 12;
    int x0 = bx * 32 - 2, y0 = by * 8 - 2;

    for (int p = tid; p < 432; p += 256) {
        int py = p / 36, px = p % 36;
        int gy = y0 + py, gx = x0 + px;
        bool ok = ((unsigned)gy < (unsigned)HW) && ((unsigned)gx < (unsigned)HW);
        int gofs = ok ? (gy * HW + gx) : 0;
#pragma unroll
        for (int c = 0; c < 8; ++c) {
            float v = h2[c * PLANE + gofs];
            tile[c][py][px] = ok ? v : 0.f;
        }
    }
    __syncthreads();

    float a = 0.f;
#pragma unroll 1
    for (int c = 0; c < 8; ++c) {
#pragma unroll
        for (int ky = 0; ky < 5; ++ky) {
#pragma unroll
            for (int kx = 0; kx < 5; ++kx) {
                a = fmaf(tile[c][ty + ky][tx + kx], W[W3_OFF + (c * 5 + ky) * 5 + kx], a);
            }
        }
    }
    float y = fmaf(a, W[SC3_OFF], W[SH3_OFF]);
    float s = 1.f / (1.f + expf(-y));
    int d = (int)floorf(s * (16.f - 1e-5f));

    int gy = by * 8 + ty, gx = bx * 32 + tx;
    depth[gy * HW + gx] = d;
}

// ---------------- final: sparse 3d conv gather + divide + albedo ----------------
__global__ __launch_bounds__(256) void final_kernel(
    const float* __restrict__ light, const float* __restrict__ albedo,
    const float* __restrict__ W, const float* __restrict__ fb,
    float* __restrict__ out)
{
    __shared__ float fw[5488];
    __shared__ float ltile[3][14][38];
    __shared__ int   dtile[14][38];

    int tid = threadIdx.x;
    int tx = tid & 31, ty = tid >> 5;
    int bx = blockIdx.x % 12, by = blockIdx.x / 12;
    int x0 = bx * 32 - 3, y0 = by * 8 - 3;

    for (int i = tid; i < 5488; i += 256) fw[i] = W[FWT_OFF + i];

    const int* dmap = ((const int*)W) + DEPTH_OFF;
    for (int p = tid; p < 14 * 38; p += 256) {
        int py = p / 38, px = p % 38;
        int gy = y0 + py, gx = x0 + px;
        bool ok = ((unsigned)gy < (unsigned)HW) && ((unsigned)gx < (unsigned)HW);
        int gofs = ok ? (gy * HW + gx) : 0;
        int dv = dmap[gofs];
        dtile[py][px] = ok ? dv : -1000;
#pragma unroll
        for (int c = 0; c < 3; ++c) {
            float lv = light[c * PLANE + gofs];
            ltile[c][py][px] = ok ? lv : 0.f;
        }
    }
    __syncthreads();

    int d0 = dtile[ty + 3][tx + 3];
    float a0 = fb[0], a1 = fb[1], a2 = fb[2], a3 = fb[3];
    const float4* fw4 = (const float4*)fw;

#pragma unroll 1
    for (int dy = 0; dy < 7; ++dy) {
#pragma unroll
        for (int dx = 0; dx < 7; ++dx) {
            int dd = dtile[ty + dy][tx + dx];
            int dz = dd - d0 + 3;
            if ((unsigned)dz < 7u) {
                int s = (dz * 7 + dy) * 7 + dx;
                float4 w0 = fw4[s * 4 + 0];
                float4 w1 = fw4[s * 4 + 1];
                float4 w2 = fw4[s * 4 + 2];
                float4 w3 = fw4[s * 4 + 3];
                float l0 = ltile[0][ty + dy][tx + dx];
                float l1 = ltile[1][ty + dy][tx + dx];
                float l2 = ltile[2][ty + dy][tx + dx];
                a0 += l0 * w0.x + l1 * w1.x + l2 * w2.x + w3.x;
                a1 += l0 * w0.y + l1 * w1.y + l2 * w2.y + w3.y;
                a2 += l0 * w0.z + l1 * w1.z + l2 * w2.z + w3.z;
                a3 += l0 * w0.w + l1 * w1.w + l2 * w2.w + w3.w;
            }
        }
    }

    int gy = by * 8 + ty, gx = bx * 32 + tx;
    int pix = gy * HW + gx;
    out[0 * PLANE + pix] = a0 / a3 * albedo[0 * PLANE + pix];
    out[1 * PLANE + pix] = a1 / a3 * albedo[1 * PLANE + pix];
    out[2 * PLANE + pix] = a2 / a3 * albedo[2 * PLANE + pix];
}

extern "C" void kernel_launch(void* const* d_in, const int* in_sizes, int n_in,
                              void* d_out, int out_size, void* d_ws, size_t ws_size,
                              hipStream_t stream) {
    const float* light     = (const float*)d_in[0];
    const float* albedo    = (const float*)d_in[1];
    const float* normals   = (const float*)d_in[2];
    // d_in[3] positions: unused by the reference
    const float* c1_w = (const float*)d_in[4];
    const float* c1_b = (const float*)d_in[5];
    const float* bn1_g = (const float*)d_in[6];
    const float* bn1_b = (const float*)d_in[7];
    const float* bn1_m = (const float*)d_in[8];
    const float* bn1_v = (const float*)d_in[9];
    const float* c2_w = (const float*)d_in[10];
    const float* c2_b = (const float*)d_in[11];
    const float* bn2_g = (const float*)d_in[12];
    const float* bn2_b = (const float*)d_in[13];
    const float* bn2_m = (const float*)d_in[14];
    const float* bn2_v = (const float*)d_in[15];
    const float* c3_w = (const float*)d_in[16];
    const float* c3_b = (const float*)d_in[17];
    const float* bn3_g = (const float*)d_in[18];
    const float* bn3_b = (const float*)d_in[19];
    const float* bn3_m = (const float*)d_in[20];
    const float* bn3_v = (const float*)d_in[21];
    const float* f_w = (const float*)d_in[22];
    const float* f_b = (const float*)d_in[23];

    float* W = (float*)d_ws;
    float* h1 = W + H1_OFF;
    float* h2 = W + H2_OFF;
    int* depth = ((int*)d_ws) + DEPTH_OFF;
    float* out = (float*)d_out;

    hipLaunchKernelGGL(prep_kernel, dim3(16), dim3(256), 0, stream,
                       c1_w, c1_b, bn1_g, bn1_b, bn1_m, bn1_v,
                       c2_w, c2_b, bn2_g, bn2_b, bn2_m, bn2_v,
                       c3_w, c3_b, bn3_g, bn3_b, bn3_m, bn3_v,
                       f_w, W);
    hipLaunchKernelGGL(conv1_kernel, dim3(576), dim3(256), 0, stream,
                       light, albedo, normals, W, h1);
    hipLaunchKernelGGL(conv2_kernel, dim3(576), dim3(256), 0, stream,
                       h1, W, h2);
    hipLaunchKernelGGL(conv3_kernel, dim3(576), dim3(256), 0, stream,
                       h2, W, depth);
    hipLaunchKernelGGL(final_kernel, dim3(576), dim3(256), 0, stream,
                       light, albedo, W, f_b, out);
}